// Round 2
// baseline (419.765 us; speedup 1.0000x reference)
//
#include <hip/hip_runtime.h>

#define IN_C  128
#define HID_C 128
#define OUT_C 64
#define NPB      128      // nodes per bucket (pow2)
#define NPB_SH   7
#define NPB_MASK 127
#define MAXB     2048     // max buckets in LDS fast path (N <= 262144)
#define CAP      6144     // pass-2 LDS staging capacity
#define B1_CHUNK 8192     // edges per pass-1 block

typedef __attribute__((ext_vector_type(8))) short short8;
typedef __attribute__((ext_vector_type(4))) float f32x4;
typedef __attribute__((ext_vector_type(4))) unsigned int u32x4;

__device__ __forceinline__ unsigned short f2bf(float f) {
    unsigned u = __float_as_uint(f);
    unsigned r = (u + 0x7FFFu + ((u >> 16) & 1u)) >> 16;
    return (unsigned short)r;
}
__device__ __forceinline__ float bf_lo(unsigned u) { return __uint_as_float(u << 16); }
__device__ __forceinline__ float bf_hi(unsigned u) { return __uint_as_float(u & 0xFFFF0000u); }

// ---- CSR build -------------------------------------------------------------

__global__ __launch_bounds__(256) void hist_kernel(const int* __restrict__ dst,
                                                   int* __restrict__ bhist,
                                                   int E, int B) {
    __shared__ int lh[MAXB];
    int t = threadIdx.x;
    int e0 = blockIdx.x * B1_CHUNK;
    int nE = min(B1_CHUNK, E - e0);
    if (B <= MAXB) {
        for (int i = t; i < B; i += 256) lh[i] = 0;
        __syncthreads();
        for (int i = t; i < nE; i += 256) atomicAdd(&lh[dst[e0 + i] >> NPB_SH], 1);
        __syncthreads();
        for (int i = t; i < B; i += 256)
            if (lh[i]) atomicAdd(&bhist[i], lh[i]);
    } else {
        for (int i = t; i < nE; i += 256) atomicAdd(&bhist[dst[e0 + i] >> NPB_SH], 1);
    }
}

__global__ __launch_bounds__(1024) void scan_bucket_kernel(const int* __restrict__ bhist,
                                                           int* __restrict__ bbase,
                                                           int* __restrict__ bcur, int B) {
    __shared__ int sums[1024];
    int t = threadIdx.x;
    int chunk = (B + 1023) >> 10;
    int beg = t * chunk, end = min(beg + chunk, B);
    int s = 0;
    for (int i = beg; i < end; ++i) s += bhist[i];
    sums[t] = s;
    __syncthreads();
    for (int off = 1; off < 1024; off <<= 1) {
        int v = (t >= off) ? sums[t - off] : 0;
        __syncthreads();
        sums[t] += v;
        __syncthreads();
    }
    int run = (t == 0) ? 0 : sums[t - 1];
    for (int i = beg; i < end; ++i) {
        bbase[i] = run; bcur[i] = run;
        run += bhist[i];
    }
    if (t == 1023) bbase[B] = sums[1023];
}

__global__ __launch_bounds__(256) void bucket_kernel(const int* __restrict__ src,
                                                     const int* __restrict__ dst,
                                                     int* __restrict__ bcur,
                                                     int* __restrict__ ebuf,
                                                     int E, int B) {
    __shared__ int hist[MAXB];
    __shared__ int runb[MAXB];
    int t = threadIdx.x;
    int e0 = blockIdx.x * B1_CHUNK;
    int nE = min(B1_CHUNK, E - e0);
    if (B <= MAXB) {
        for (int i = t; i < B; i += 256) hist[i] = 0;
        __syncthreads();
        for (int i = t; i < nE; i += 256) atomicAdd(&hist[dst[e0 + i] >> NPB_SH], 1);
        __syncthreads();
        for (int i = t; i < B; i += 256) {
            int c = hist[i];
            runb[i] = c ? atomicAdd(&bcur[i], c) : 0;
            hist[i] = 0;
        }
        __syncthreads();
        for (int i = t; i < nE; i += 256) {
            int d = dst[e0 + i], s = src[e0 + i];
            int b = d >> NPB_SH;
            int off2 = atomicAdd(&hist[b], 1);
            ebuf[runb[b] + off2] = (s << NPB_SH) | (d & NPB_MASK);
        }
    } else {
        for (int i = t; i < nE; i += 256) {
            int d = dst[e0 + i], s = src[e0 + i];
            int pos = atomicAdd(&bcur[d >> NPB_SH], 1);
            ebuf[pos] = (s << NPB_SH) | (d & NPB_MASK);
        }
    }
}

__global__ __launch_bounds__(256) void csr_kernel(const int* __restrict__ ebuf,
                                                  const int* __restrict__ bbase,
                                                  int* __restrict__ col,
                                                  int* __restrict__ rowptr,
                                                  float* __restrict__ dinv,
                                                  int N, int E) {
    __shared__ int sorted[CAP];
    __shared__ int lhist[NPB];
    __shared__ int lpre[NPB + 1];
    int b = blockIdx.x;
    int t = threadIdx.x;
    int base = bbase[b], size = bbase[b + 1] - base;
    int node_base = b << NPB_SH;
    int nn = min(NPB, N - node_base);

    if (t < NPB) lhist[t] = 0;
    __syncthreads();
    for (int i = t; i < size; i += 256) atomicAdd(&lhist[ebuf[base + i] & NPB_MASK], 1);
    __syncthreads();
    if (t < NPB) lpre[t + 1] = lhist[t];
    if (t == 0) lpre[0] = 0;
    __syncthreads();
    for (int off = 1; off < NPB; off <<= 1) {
        int v = (t >= off && t < NPB) ? lpre[t + 1 - off] : 0;
        __syncthreads();
        if (t < NPB) lpre[t + 1] += v;
        __syncthreads();
    }
    if (t < nn) {
        rowptr[node_base + t] = base + lpre[t];
        dinv[node_base + t] = rsqrtf((float)(lhist[t] + 1));
    }
    if (node_base + nn == N && t == 0) rowptr[N] = base + size;
    if (t < NPB) lhist[t] = lpre[t];
    __syncthreads();
    if (size <= CAP) {
        for (int i = t; i < size; i += 256) {
            int entry = ebuf[base + i];
            int slot = atomicAdd(&lhist[entry & NPB_MASK], 1);
            sorted[slot] = entry >> NPB_SH;
        }
        __syncthreads();
        for (int i = t; i < size; i += 256) col[base + i] = sorted[i];
    } else {
        for (int i = t; i < size; i += 256) {
            int entry = ebuf[base + i];
            int slot = atomicAdd(&lhist[entry & NPB_MASK], 1);
            col[base + slot] = entry >> NPB_SH;
        }
    }
}

// ---- MFMA dense transform --------------------------------------------------
// Output Hs is SLICE-MAJOR: [C/16][n][16] bf16 (32 B per node per slice), so
// the aggregation kernel's per-XCD channel slice is a 3.2 MB contiguous block
// that fits a 4 MB per-XCD L2. For ushort input (layer 2), X is slice-major
// with 128 input channels: [8][n][16].

template<int C, typename InT>
__global__ __launch_bounds__(256) void mm_mfma_kernel(
    const InT* __restrict__ X, const float* __restrict__ W,
    const float* __restrict__ dinv, unsigned short* __restrict__ Hs, int n) {
    constexpr int LD = 136;
    __shared__ unsigned short Wt[C][LD];
    int t = threadIdx.x;

    for (int i = t; i < (128 * C) / 4; i += 256) {
        int idx = i * 4;
        int k = idx / C, c = idx % C;
        float4 wv = *(const float4*)&W[(size_t)k * C + c];
        Wt[c + 0][k] = f2bf(wv.x);
        Wt[c + 1][k] = f2bf(wv.y);
        Wt[c + 2][k] = f2bf(wv.z);
        Wt[c + 3][k] = f2bf(wv.w);
    }
    __syncthreads();

    int w = t >> 6, lane = t & 63;
    int m = lane & 15, quad = lane >> 4;
    int row0 = blockIdx.x * 64 + w * 16;
    int arow = min(row0 + m, n - 1);

    constexpr int NT = C / 16;
    f32x4 acc[NT];
#pragma unroll
    for (int ct = 0; ct < NT; ++ct) acc[ct] = (f32x4){0.f, 0.f, 0.f, 0.f};

#pragma unroll
    for (int kk = 0; kk < 4; ++kk) {
        int k0 = kk * 32 + quad * 8;
        short8 a;
        if constexpr (sizeof(InT) == 4) {
            const float* xp = (const float*)X + (size_t)arow * 128 + k0;
            float4 f0 = *(const float4*)xp;
            float4 f1 = *(const float4*)(xp + 4);
            a[0] = (short)f2bf(f0.x); a[1] = (short)f2bf(f0.y);
            a[2] = (short)f2bf(f0.z); a[3] = (short)f2bf(f0.w);
            a[4] = (short)f2bf(f1.x); a[5] = (short)f2bf(f1.y);
            a[6] = (short)f2bf(f1.z); a[7] = (short)f2bf(f1.w);
        } else {
            // slice-major input: slice = k0/16, offset = k0%16
            const unsigned short* xp = (const unsigned short*)X;
            int slice = k0 >> 4;
            a = *(const short8*)(xp + (size_t)slice * n * 16 + (size_t)arow * 16 + (k0 & 15));
        }
#pragma unroll
        for (int ct = 0; ct < NT; ++ct) {
            short8 b = *(const short8*)&Wt[ct * 16 + m][k0];
            acc[ct] = __builtin_amdgcn_mfma_f32_16x16x32_bf16(a, b, acc[ct], 0, 0, 0);
        }
    }

    int qrow = row0 + quad * 4;
    float dv[4];
#pragma unroll
    for (int r = 0; r < 4; ++r) dv[r] = (qrow + r < n) ? dinv[qrow + r] : 0.f;
#pragma unroll
    for (int ct = 0; ct < NT; ++ct) {
        // column ct*16+m  ->  slice ct, within-slice offset m
        unsigned short* hp = Hs + (size_t)ct * n * 16 + m;
#pragma unroll
        for (int r = 0; r < 4; ++r) {
            int row = qrow + r;
            if (row < n) hp[(size_t)row * 16] = f2bf(acc[ct][r] * dv[r]);
        }
    }
}

// ---- aggregation: out[d] = dinv[d]*(Hs[d] + sum_{s in N(d)} Hs[s]) + b -----
// Channel-sliced + XCD-affine. Hs is slice-major [C/16][n][16] bf16; one
// slice = n*32 B = 3.2 MB @ n=100k -> fits a 4 MB per-XCD L2. slice =
// blockIdx % NS pins each XCD (round-robin dispatch) to ONE slice, so after
// the cold fill all random gathers are L2 hits instead of LLC/HBM misses.
// Two lanes per destination node walk its CSR edge list serially (no
// cross-lane reduction); col/rowptr streamed nontemporally so they don't
// evict the resident slice.

template<int C, bool BOUT>
__global__ __launch_bounds__(256) void agg_slice_kernel(
    const unsigned short* __restrict__ Hs, const float* __restrict__ bias,
    const float* __restrict__ dinv, const int* __restrict__ rowptr,
    const int* __restrict__ col, void* __restrict__ outv, int n, int relu) {
    constexpr int NS = C / 16;
    int sb = blockIdx.x % NS;           // channel slice (== XCD id mod NS)
    int blk = blockIdx.x / NS;          // node block
    int d = blk * 128 + (threadIdx.x >> 1);
    if (d >= n) return;
    int half = threadIdx.x & 1;
    const unsigned short* hsl = Hs + (size_t)sb * n * 16;

    int beg = __builtin_nontemporal_load(&rowptr[d]);
    int end = __builtin_nontemporal_load(&rowptr[d + 1]);

    float acc[8];
    uint4 v0 = *((const uint4*)(hsl + (size_t)d * 16) + half);   // self row
    acc[0] = bf_lo(v0.x); acc[1] = bf_hi(v0.x);
    acc[2] = bf_lo(v0.y); acc[3] = bf_hi(v0.y);
    acc[4] = bf_lo(v0.z); acc[5] = bf_hi(v0.z);
    acc[6] = bf_lo(v0.w); acc[7] = bf_hi(v0.w);

    int j = beg;
    for (; j + 4 <= end; j += 4) {
        int c0 = __builtin_nontemporal_load(col + j);
        int c1 = __builtin_nontemporal_load(col + j + 1);
        int c2 = __builtin_nontemporal_load(col + j + 2);
        int c3 = __builtin_nontemporal_load(col + j + 3);
        uint4 v[4];
        v[0] = *((const uint4*)(hsl + (size_t)c0 * 16) + half);
        v[1] = *((const uint4*)(hsl + (size_t)c1 * 16) + half);
        v[2] = *((const uint4*)(hsl + (size_t)c2 * 16) + half);
        v[3] = *((const uint4*)(hsl + (size_t)c3 * 16) + half);
#pragma unroll
        for (int b = 0; b < 4; ++b) {
            acc[0] += bf_lo(v[b].x); acc[1] += bf_hi(v[b].x);
            acc[2] += bf_lo(v[b].y); acc[3] += bf_hi(v[b].y);
            acc[4] += bf_lo(v[b].z); acc[5] += bf_hi(v[b].z);
            acc[6] += bf_lo(v[b].w); acc[7] += bf_hi(v[b].w);
        }
    }
    for (; j < end; ++j) {
        int c0 = __builtin_nontemporal_load(col + j);
        uint4 v = *((const uint4*)(hsl + (size_t)c0 * 16) + half);
        acc[0] += bf_lo(v.x); acc[1] += bf_hi(v.x);
        acc[2] += bf_lo(v.y); acc[3] += bf_hi(v.y);
        acc[4] += bf_lo(v.z); acc[5] += bf_hi(v.z);
        acc[6] += bf_lo(v.w); acc[7] += bf_hi(v.w);
    }

    float dv = dinv[d];
    const float* bp = bias + sb * 16 + half * 8;
    float4 b0 = *(const float4*)bp;
    float4 b1 = *(const float4*)(bp + 4);
    float r[8];
    r[0] = dv * acc[0] + b0.x; r[1] = dv * acc[1] + b0.y;
    r[2] = dv * acc[2] + b0.z; r[3] = dv * acc[3] + b0.w;
    r[4] = dv * acc[4] + b1.x; r[5] = dv * acc[5] + b1.y;
    r[6] = dv * acc[6] + b1.z; r[7] = dv * acc[7] + b1.w;
    if (relu) {
#pragma unroll
        for (int k = 0; k < 8; ++k) r[k] = fmaxf(r[k], 0.f);
    }
    if constexpr (BOUT) {
        // slice-major bf16 output (feeds mm_mfma sliced input)
        u32x4 o;
        o.x = (unsigned)f2bf(r[0]) | ((unsigned)f2bf(r[1]) << 16);
        o.y = (unsigned)f2bf(r[2]) | ((unsigned)f2bf(r[3]) << 16);
        o.z = (unsigned)f2bf(r[4]) | ((unsigned)f2bf(r[5]) << 16);
        o.w = (unsigned)f2bf(r[6]) | ((unsigned)f2bf(r[7]) << 16);
        u32x4* op = (u32x4*)((unsigned short*)outv + (size_t)sb * n * 16 + (size_t)d * 16 + half * 8);
        __builtin_nontemporal_store(o, op);
    } else {
        // row-major fp32 final output
        float* o = (float*)outv + (size_t)d * C + sb * 16 + half * 8;
        f32x4 o0 = {r[0], r[1], r[2], r[3]};
        f32x4 o1 = {r[4], r[5], r[6], r[7]};
        __builtin_nontemporal_store(o0, (f32x4*)o);
        __builtin_nontemporal_store(o1, (f32x4*)o + 1);
    }
}

// ---- driver ----------------------------------------------------------------

extern "C" void kernel_launch(void* const* d_in, const int* in_sizes, int n_in,
                              void* d_out, int out_size, void* d_ws, size_t ws_size,
                              hipStream_t stream) {
    const float* x  = (const float*)d_in[0];
    const int*   ei = (const int*)d_in[1];
    const float* W1 = (const float*)d_in[2];
    const float* b1 = (const float*)d_in[3];
    const float* W2 = (const float*)d_in[4];
    const float* b2 = (const float*)d_in[5];
    float* out = (float*)d_out;

    int N = in_sizes[0] / IN_C;
    int E = in_sizes[1] / 2;
    const int* src = ei;
    const int* dst = ei + E;
    int B = (N + NPB - 1) >> NPB_SH;

    char* ws = (char*)d_ws;
    size_t off = 0;
    int*   bhist  = (int*)(ws + off);   off += (size_t)B * 4;
    int*   bbase  = (int*)(ws + off);   off += (size_t)(B + 1) * 4;
    int*   bcur   = (int*)(ws + off);   off += (size_t)B * 4;
    float* dinv   = (float*)(ws + off); off += (size_t)N * 4;
    int*   rowptr = (int*)(ws + off);   off += (size_t)(N + 1) * 4;
    off = (off + 15) & ~(size_t)15;
    int*   ebuf   = (int*)(ws + off);   off += (size_t)E * 4;
    int*   col    = (int*)(ws + off);   off += (size_t)E * 4;
    off = (off + 15) & ~(size_t)15;
    unsigned short* H1  = (unsigned short*)(ws + off); off += (size_t)N * HID_C * 2;
    off = (off + 15) & ~(size_t)15;
    unsigned short* AG1 = (unsigned short*)(ws + off); off += (size_t)N * HID_C * 2;
    unsigned short* H2 = H1;

    hipMemsetAsync(bhist, 0, (size_t)B * 4, stream);

    int nblk = (E + B1_CHUNK - 1) / B1_CHUNK;
    hist_kernel<<<nblk, 256, 0, stream>>>(dst, bhist, E, B);
    scan_bucket_kernel<<<1, 1024, 0, stream>>>(bhist, bbase, bcur, B);
    bucket_kernel<<<nblk, 256, 0, stream>>>(src, dst, bcur, ebuf, E, B);
    csr_kernel<<<B, 256, 0, stream>>>(ebuf, bbase, col, rowptr, dinv, N, E);

    int mblk = (N + 63) / 64;
    int ablk = (N + 127) >> 7;   // node blocks for agg (128 nodes per block)

    mm_mfma_kernel<HID_C, float><<<mblk, 256, 0, stream>>>(x, W1, dinv, H1, N);
    agg_slice_kernel<HID_C, true><<<ablk * (HID_C / 16), 256, 0, stream>>>(
        H1, b1, dinv, rowptr, col, AG1, N, 1);

    mm_mfma_kernel<OUT_C, unsigned short><<<mblk, 256, 0, stream>>>(AG1, W2, dinv, H2, N);
    agg_slice_kernel<OUT_C, false><<<ablk * (OUT_C / 16), 256, 0, stream>>>(
        H2, b2, dinv, rowptr, col, out, N, 0);
}